// Round 3
// baseline (91.201 us; speedup 1.0000x reference)
//
#include <hip/hip_runtime.h>
#include <hip/hip_bf16.h>
#include <cstdint>

#define NROWS 8192
#define NPER  4096
#define DIM   512
#define TEMP_INV 10.0f
#define NB2 32          // 8192 / 256 row-blocks
#define NBLK 528        // NB2*(NB2+1)/2

typedef __bf16 bf16x8 __attribute__((ext_vector_type(8)));
typedef float  f32x4  __attribute__((ext_vector_type(4)));

__device__ __forceinline__ unsigned short f2bf(float f) {
  unsigned int u = __builtin_bit_cast(unsigned int, f);
  u += 0x7FFFu + ((u >> 16) & 1u);
  return (unsigned short)(u >> 16);
}

// ---------------------------------------------------------------------------
// Kernel 1: L2-normalize rows of [view0; view1] -> z (bf16, [8192][512]).
// Also zeroes rowsum (replaces hipMemsetAsync dispatch).
// ---------------------------------------------------------------------------
__global__ __launch_bounds__(256) void k_normalize(const float* __restrict__ v0,
                                                   const float* __restrict__ v1,
                                                   unsigned short* __restrict__ z,
                                                   float* __restrict__ rowsum) {
  if (blockIdx.x < 32) rowsum[blockIdx.x * 256 + threadIdx.x] = 0.f;
  const int wid  = (blockIdx.x * 256 + threadIdx.x) >> 6;  // row
  const int lane = threadIdx.x & 63;
  if (wid >= NROWS) return;
  const float* src = (wid < NPER) ? (v0 + (size_t)wid * DIM)
                                  : (v1 + (size_t)(wid - NPER) * DIM);
  float4 a = *(const float4*)(src + lane * 8);
  float4 b = *(const float4*)(src + lane * 8 + 4);
  float ss = a.x*a.x + a.y*a.y + a.z*a.z + a.w*a.w
           + b.x*b.x + b.y*b.y + b.z*b.z + b.w*b.w;
  #pragma unroll
  for (int m = 1; m < 64; m <<= 1) ss += __shfl_xor(ss, m);
  float inv = 1.0f / fmaxf(sqrtf(ss), 1e-12f);
  union { unsigned short us[8]; uint4 v; } p;
  p.us[0] = f2bf(a.x * inv); p.us[1] = f2bf(a.y * inv);
  p.us[2] = f2bf(a.z * inv); p.us[3] = f2bf(a.w * inv);
  p.us[4] = f2bf(b.x * inv); p.us[5] = f2bf(b.y * inv);
  p.us[6] = f2bf(b.z * inv); p.us[7] = f2bf(b.w * inv);
  *(uint4*)(z + (size_t)wid * DIM + lane * 8) = p.v;
}

// ---------------------------------------------------------------------------
// Kernel 2: symmetric fused G = z z^T, 256x256 upper-triangular blocks,
// 8 waves (2x4), per-wave 128x64 (acc[8][4]), BK=64 double-buffered.
// m201-faithful fine-grained phase interleave (T3+T4+T5):
//   per K-tile j (slot s = j&1), 4 phases p = (kk<<1 | mh):
//     phase body: [ds_read 4-8 b128 from slot s] [stage 0-2 chunks of
//     KT j+1 -> slot s^1] [p==0: vmcnt(4) AFTER issuing new loads -> never
//     drains to 0] [s_barrier] [lgkmcnt(0)] [setprio(1) 16 MFMA setprio(0)]
//     [s_barrier]
//   Staging spread: chunks {i0,i1} at p0, {i2} at p1, {i3} at p2 -> at the
//   next K-tile's p0 certify-wait, the youngest needed load is >=2 phases
//   (~600+ cyc) old: counted vmcnt, no drain-to-0 until the last K-tile.
//   Slot-reuse safety: every phase drains its ds_reads (lgkmcnt(0)) before
//   its end barrier; stages into slot s^1 are issued only after the end
//   barrier of the last phase that read s^1 (previous K-tile, p3).
// T2 XOR-swizzled LDS (linear dest + pre-swizzled global source, rule #21),
// T1 chunked XCD block swizzle (528 % 8 == 0).
// Positive-pair dots harvested from raw acc of tiles with bj-bi == 16.
// ---------------------------------------------------------------------------
__global__ __launch_bounds__(512, 2) void k_gemm_sym(const unsigned short* __restrict__ z,
                                                     float* __restrict__ rowsum,
                                                     float* __restrict__ s) {
  __shared__ __align__(16) unsigned short As[2][256 * 64];
  __shared__ __align__(16) unsigned short Bs[2][256 * 64];
  __shared__ float racc[4][256];   // [wc][row-in-block] partial row sums
  __shared__ float cacc[2][256];   // [wr][col-in-block] partial col sums

  const int tid  = threadIdx.x;
  const int lane = tid & 63;
  const int w    = tid >> 6;      // 0..7
  const int wr   = w >> 2;        // 0..1 (row half)
  const int wc   = w & 3;         // 0..3 (col quarter)

  // T1: bijective chunked XCD swizzle (528 % 8 == 0)
  const int orig = blockIdx.x;
  const int t = (orig & 7) * (NBLK / 8) + (orig >> 3);
  // decode upper-triangular block (bi <= bj)
  int bi = (int)((65.0f - sqrtf((float)(4225 - 8 * t))) * 0.5f);
  while ((bi + 1) * NB2 - ((bi + 1) * bi) / 2 <= t) ++bi;
  while (bi * NB2 - (bi * (bi - 1)) / 2 > t) --bi;
  const int bj   = bi + (t - (bi * NB2 - (bi * (bi - 1)) / 2));
  const int brow = bi * 256;
  const int bcol = bj * 256;
  const bool diag   = (bi == bj);
  const bool pair16 = (bj - bi == 16);   // tile contains positive-pair diagonal

  f32x4 acc[8][4];
  const f32x4 zero = {0.f, 0.f, 0.f, 0.f};
  #pragma unroll
  for (int m = 0; m < 8; ++m)
    #pragma unroll
    for (int n = 0; n < 4; ++n) acc[m][n] = zero;

  // stage one chunk (8 rows of A + 8 rows of B, 2 global_load_lds) of a
  // BK=64 K-slab. LDS dest linear; global source pre-swizzled (rule #21):
  // phys_byte = logical_byte ^ ((row & 7) << 4).
  const int srow = (lane >> 3);                  // 0..7 row within chunk
  const int skof = 8 * ((lane & 7) ^ srow);      // pre-swizzled k-offset (elems)
  auto stage_one = [&](int buf, int k0, int i) {
    const int c = w * 4 + i;                     // chunk 0..31 (8 rows each)
    const int row_in = c * 8 + srow;
    const unsigned short* ga = z + (size_t)(brow + row_in) * DIM + k0 + skof;
    const unsigned short* gb = z + (size_t)(bcol + row_in) * DIM + k0 + skof;
    __builtin_amdgcn_global_load_lds(
        (const __attribute__((address_space(1))) void*)ga,
        (__attribute__((address_space(3))) void*)(&As[buf][c * 512]), 16, 0, 0);
    __builtin_amdgcn_global_load_lds(
        (const __attribute__((address_space(1))) void*)gb,
        (__attribute__((address_space(3))) void*)(&Bs[buf][c * 512]), 16, 0, 0);
  };

  // prologue: stage K-tile 0 completely (8 loads/thread in flight)
  #pragma unroll
  for (int i = 0; i < 4; ++i) stage_one(0, 0, i);

  const int r0 = lane & 15;
  const int g  = lane >> 4;
  const int sw = (r0 & 7) << 4;                  // swizzle XOR (bits 4-6)

  bf16x8 bq[4];

  for (int j = 0; j < 8; ++j) {                  // K-tiles
    const int cur = j & 1;
    const char* Ab = (const char*)&As[cur][0];
    const char* Bb = (const char*)&Bs[cur][0];
    const int nk0 = (j + 1) * 64;                // next K-tile k-offset
    const bool pre = (j < 7);

    #pragma unroll
    for (int p = 0; p < 4; ++p) {                // phases: p = kk*2 + mh
      const int kk = p >> 1;
      const int mh = p & 1;
      const int kb = kk * 64 + g * 16;           // k byte-offset within row
      bf16x8 aq[4];

      if (p == 0) {
        // certify slot cur (KT j): issue 2 chunks of KT j+1 first, then
        // counted wait -> KT j drained, 4 newest loads stay in flight.
        if (pre) { stage_one(cur ^ 1, nk0, 0); stage_one(cur ^ 1, nk0, 1); }
        if (pre) asm volatile("s_waitcnt vmcnt(4)" ::: "memory");
        else     asm volatile("s_waitcnt vmcnt(0)" ::: "memory");
        __builtin_amdgcn_s_barrier();            // all waves: KT j visible
        #pragma unroll
        for (int n = 0; n < 4; ++n)
          bq[n] = *(const bf16x8*)(Bb + (((wc * 64 + n * 16 + r0) * 128 + kb) ^ sw));
        #pragma unroll
        for (int m = 0; m < 4; ++m)
          aq[m] = *(const bf16x8*)(Ab + (((wr * 128 + m * 16 + r0) * 128 + kb) ^ sw));
      } else {
        if (mh == 0) {                           // p==2: B frags for kk=1
          #pragma unroll
          for (int n = 0; n < 4; ++n)
            bq[n] = *(const bf16x8*)(Bb + (((wc * 64 + n * 16 + r0) * 128 + kb) ^ sw));
        }
        #pragma unroll
        for (int m = 0; m < 4; ++m)
          aq[m] = *(const bf16x8*)(Ab + (((wr * 128 + mh * 64 + m * 16 + r0) * 128 + kb) ^ sw));
        if (pre && p == 1) stage_one(cur ^ 1, nk0, 2);
        if (pre && p == 2) stage_one(cur ^ 1, nk0, 3);
        __builtin_amdgcn_s_barrier();            // phase align (reads in flight)
      }

      asm volatile("s_waitcnt lgkmcnt(0)" ::: "memory");
      __builtin_amdgcn_sched_barrier(0);
      __builtin_amdgcn_s_setprio(1);
      #pragma unroll
      for (int m = 0; m < 4; ++m)
        #pragma unroll
        for (int n = 0; n < 4; ++n)
          acc[mh * 4 + m][n] = __builtin_amdgcn_mfma_f32_16x16x32_bf16(
              aq[m], bq[n], acc[mh * 4 + m][n], 0, 0, 0);
      __builtin_amdgcn_s_setprio(0);
      __builtin_amdgcn_s_barrier();              // phase lock / slot-free cert
    }
  }

  // ---- epilogue: exp(10*g); row sums + col sums (symmetry); pair dots ----
  float cs[4] = {0.f, 0.f, 0.f, 0.f};
  const int grow0 = brow + wr * 128;
  const int gcol0 = bcol + wc * 64;
  #pragma unroll
  for (int m = 0; m < 8; ++m) {
    #pragma unroll
    for (int j = 0; j < 4; ++j) {
      const int grow = grow0 + m * 16 + g * 4 + j;
      float v = 0.f;
      #pragma unroll
      for (int n = 0; n < 4; ++n) {
        const int gcol = gcol0 + n * 16 + r0;
        const float raw = acc[m][n][j];
        const float e = __expf(raw * TEMP_INV);
        if (grow != gcol) { v += e; cs[n] += e; }   // skip self-similarity
        if (pair16 && (grow + NPER == gcol)) {      // positive-pair raw dot
          s[grow] = raw;                            // dot(z_i, z_{i+NPER})
          s[gcol] = raw;                            // symmetric partner
        }
      }
      v += __shfl_xor(v, 1);
      v += __shfl_xor(v, 2);
      v += __shfl_xor(v, 4);
      v += __shfl_xor(v, 8);
      if (r0 == 0) racc[wc][wr * 128 + m * 16 + g * 4 + j] = v;
    }
  }
  #pragma unroll
  for (int n = 0; n < 4; ++n) {
    float v = cs[n];
    v += __shfl_xor(v, 16);
    v += __shfl_xor(v, 32);
    if (lane < 16) cacc[wr][wc * 64 + n * 16 + lane] = v;
  }
  __syncthreads();
  if (tid < 256) {
    atomicAdd(&rowsum[brow + tid],
              racc[0][tid] + racc[1][tid] + racc[2][tid] + racc[3][tid]);
  } else if (!diag) {
    const int i = tid - 256;
    atomicAdd(&rowsum[bcol + i], cacc[0][i] + cacc[1][i]);
  }
}

// ---------------------------------------------------------------------------
// Kernel 3: loss = mean_i( log(denom_i) - s_i/T )
// ---------------------------------------------------------------------------
__global__ __launch_bounds__(256) void k_loss(const float* __restrict__ rowsum,
                                              const float* __restrict__ s,
                                              float* __restrict__ out) {
  __shared__ float red[256];
  float acc = 0.f;
  for (int i = threadIdx.x; i < NROWS; i += 256)
    acc += logf(rowsum[i]) - s[i] * TEMP_INV;
  red[threadIdx.x] = acc;
  __syncthreads();
  for (int st = 128; st > 0; st >>= 1) {
    if (threadIdx.x < st) red[threadIdx.x] += red[threadIdx.x + st];
    __syncthreads();
  }
  if (threadIdx.x == 0) out[0] = red[0] / (float)NROWS;
}

extern "C" void kernel_launch(void* const* d_in, const int* in_sizes, int n_in,
                              void* d_out, int out_size, void* d_ws, size_t ws_size,
                              hipStream_t stream) {
  const float* v0 = (const float*)d_in[0];
  const float* v1 = (const float*)d_in[1];
  float* out = (float*)d_out;

  unsigned short* z = (unsigned short*)d_ws;                    // 8192*512*2 B
  float* rowsum = (float*)((char*)d_ws + (size_t)NROWS * DIM * 2);
  float* s      = rowsum + NROWS;

  k_normalize<<<NROWS / 4, 256, 0, stream>>>(v0, v1, z, rowsum);
  k_gemm_sym<<<NBLK, 512, 0, stream>>>(z, rowsum, s);
  k_loss<<<1, 256, 0, stream>>>(rowsum, s, out);
}

// Round 4
// 64.290 us; speedup vs baseline: 1.4186x; 1.4186x over previous
//
#include <hip/hip_runtime.h>
#include <hip/hip_bf16.h>
#include <cstdint>

#define NROWS 8192
#define NPER  4096
#define DIM   512
#define TEMP_INV 10.0f
#define NB    64        // 8192 / 128 row-blocks
#define NBLK  2080      // NB*(NB+1)/2 upper-tri 128x128 tiles
#define PAIR_OFF 32     // NPER / 128

typedef __bf16 bf16x8 __attribute__((ext_vector_type(8)));
typedef float  f32x4  __attribute__((ext_vector_type(4)));

__device__ __forceinline__ unsigned short f2bf(float f) {
  unsigned int u = __builtin_bit_cast(unsigned int, f);
  u += 0x7FFFu + ((u >> 16) & 1u);
  return (unsigned short)(u >> 16);
}

// ---------------------------------------------------------------------------
// Kernel 1: L2-normalize rows of [view0; view1] -> z (bf16, [8192][512]).
// Also zeroes rowsum and out (replaces memset + enables atomic k_loss).
// ---------------------------------------------------------------------------
__global__ __launch_bounds__(256) void k_normalize(const float* __restrict__ v0,
                                                   const float* __restrict__ v1,
                                                   unsigned short* __restrict__ z,
                                                   float* __restrict__ rowsum,
                                                   float* __restrict__ out) {
  if (blockIdx.x < 32) rowsum[blockIdx.x * 256 + threadIdx.x] = 0.f;
  if (blockIdx.x == 0 && threadIdx.x == 0) out[0] = 0.f;
  const int wid  = (blockIdx.x * 256 + threadIdx.x) >> 6;  // row
  const int lane = threadIdx.x & 63;
  if (wid >= NROWS) return;
  const float* src = (wid < NPER) ? (v0 + (size_t)wid * DIM)
                                  : (v1 + (size_t)(wid - NPER) * DIM);
  float4 a = *(const float4*)(src + lane * 8);
  float4 b = *(const float4*)(src + lane * 8 + 4);
  float ss = a.x*a.x + a.y*a.y + a.z*a.z + a.w*a.w
           + b.x*b.x + b.y*b.y + b.z*b.z + b.w*b.w;
  #pragma unroll
  for (int m = 1; m < 64; m <<= 1) ss += __shfl_xor(ss, m);
  float inv = 1.0f / fmaxf(sqrtf(ss), 1e-12f);
  union { unsigned short us[8]; uint4 v; } p;
  p.us[0] = f2bf(a.x * inv); p.us[1] = f2bf(a.y * inv);
  p.us[2] = f2bf(a.z * inv); p.us[3] = f2bf(a.w * inv);
  p.us[4] = f2bf(b.x * inv); p.us[5] = f2bf(b.y * inv);
  p.us[6] = f2bf(b.z * inv); p.us[7] = f2bf(b.w * inv);
  *(uint4*)(z + (size_t)wid * DIM + lane * 8) = p.v;
}

// ---------------------------------------------------------------------------
// Kernel 2: symmetric fused G = z z^T, 128x128 upper-triangular tiles,
// 4 waves (2x2), per-wave 64x64 (acc[4][4]), BK=64 SINGLE-buffered.
// Occupancy-first design (R3 post-mortem): all pipelined structures pinned
// at ~19% MfmaUtil with 2 waves/SIMD; this trades the LDS double-buffer for
// 32 KB LDS + __launch_bounds__(256,3) -> 3 independent blocks/CU
// (12 waves/CU). Cross-block TLP hides the per-iteration vmcnt(0) drain
// (m114: implicit wave-level overlap captures what source pipelining would).
// T2 XOR-swizzled LDS (linear dest + pre-swizzled global source, rule #21),
// T1 chunked XCD block swizzle (2080 % 8 == 0).
// Positive-pair dots harvested from raw acc of tiles with bj-bi == 32.
// Epilogue smem arrays aliased into As (keeps LDS at exactly 32 KB).
// ---------------------------------------------------------------------------
__global__ __launch_bounds__(256, 3) void k_gemm_sym(const unsigned short* __restrict__ z,
                                                     float* __restrict__ rowsum,
                                                     float* __restrict__ s) {
  __shared__ __align__(16) unsigned short As[128 * 64];   // 16 KB
  __shared__ __align__(16) unsigned short Bs[128 * 64];   // 16 KB

  const int tid  = threadIdx.x;
  const int lane = tid & 63;
  const int w    = tid >> 6;      // 0..3
  const int wr   = w >> 1;        // 0..1 (row half)
  const int wc   = w & 1;         // 0..1 (col half)

  // T1: bijective chunked XCD swizzle (2080 % 8 == 0)
  const int orig = blockIdx.x;
  const int t = (orig & 7) * (NBLK / 8) + (orig >> 3);
  // decode upper-triangular block (bi <= bj): start(bi) = bi*NB - bi(bi-1)/2
  int bi = (int)((129.0f - sqrtf((float)(16641 - 8 * t))) * 0.5f);
  while ((bi + 1) * NB - ((bi + 1) * bi) / 2 <= t) ++bi;
  while (bi * NB - (bi * (bi - 1)) / 2 > t) --bi;
  const int bj   = bi + (t - (bi * NB - (bi * (bi - 1)) / 2));
  const int brow = bi * 128;
  const int bcol = bj * 128;
  const bool diag = (bi == bj);
  const bool pair = (bj - bi == PAIR_OFF);  // contains positive-pair diagonal

  f32x4 acc[4][4];
  const f32x4 zero = {0.f, 0.f, 0.f, 0.f};
  #pragma unroll
  for (int m = 0; m < 4; ++m)
    #pragma unroll
    for (int n = 0; n < 4; ++n) acc[m][n] = zero;

  // stage one BK=64 K-slab (A and B tiles, 16 KB each). 8 global_load_lds
  // per thread. LDS dest linear; global source pre-swizzled (rule #21):
  // phys_byte = logical_byte ^ ((row & 7) << 4).
  const int srow = (lane >> 3);                  // 0..7 row within chunk
  const int skof = 8 * ((lane & 7) ^ srow);      // pre-swizzled k-offset (elems)
  auto stage = [&](int k0) {
    #pragma unroll
    for (int i = 0; i < 4; ++i) {
      const int c = w * 4 + i;                   // chunk 0..15 (8 rows each)
      const int row_in = c * 8 + srow;
      const unsigned short* ga = z + (size_t)(brow + row_in) * DIM + k0 + skof;
      const unsigned short* gb = z + (size_t)(bcol + row_in) * DIM + k0 + skof;
      __builtin_amdgcn_global_load_lds(
          (const __attribute__((address_space(1))) void*)ga,
          (__attribute__((address_space(3))) void*)(&As[c * 512]), 16, 0, 0);
      __builtin_amdgcn_global_load_lds(
          (const __attribute__((address_space(1))) void*)gb,
          (__attribute__((address_space(3))) void*)(&Bs[c * 512]), 16, 0, 0);
    }
  };

  const int r0 = lane & 15;
  const int g  = lane >> 4;
  const int sw = (r0 & 7) << 4;                  // swizzle XOR (bits 4-6)

  for (int kt = 0; kt < 8; ++kt) {
    stage(kt * 64);
    // single buffer: own loads drained, then all waves' loads visible.
    asm volatile("s_waitcnt vmcnt(0)" ::: "memory");
    __builtin_amdgcn_s_barrier();

    const char* Ab = (const char*)&As[0];
    const char* Bb = (const char*)&Bs[0];
    #pragma unroll
    for (int kk = 0; kk < 2; ++kk) {
      const int kb = kk * 64 + g * 16;           // k byte-offset within row
      bf16x8 bfrag[4];
      #pragma unroll
      for (int n = 0; n < 4; ++n)
        bfrag[n] = *(const bf16x8*)(Bb + (((wc * 64 + n * 16 + r0) * 128 + kb) ^ sw));
      #pragma unroll
      for (int m = 0; m < 4; ++m) {
        bf16x8 afrag = *(const bf16x8*)(Ab + (((wr * 64 + m * 16 + r0) * 128 + kb) ^ sw));
        #pragma unroll
        for (int n = 0; n < 4; ++n)
          acc[m][n] = __builtin_amdgcn_mfma_f32_16x16x32_bf16(afrag, bfrag[n],
                                                              acc[m][n], 0, 0, 0);
      }
    }
    // all LDS reads done in this wave, sync all waves -> safe to overwrite.
    asm volatile("s_waitcnt lgkmcnt(0)" ::: "memory");
    __builtin_amdgcn_sched_barrier(0);
    __builtin_amdgcn_s_barrier();
  }

  // ---- epilogue: exp(10*g); row sums + col sums (symmetry); pair dots ----
  // smem reduction arrays aliased into As (all LDS reads drained above).
  float (*racc)[128] = (float (*)[128])As;        // [2][128]
  float (*cacc)[128] = ((float (*)[128])As) + 2;  // [2][128]

  float cs[4] = {0.f, 0.f, 0.f, 0.f};
  const int grow0 = brow + wr * 64;
  const int gcol0 = bcol + wc * 64;
  #pragma unroll
  for (int m = 0; m < 4; ++m) {
    #pragma unroll
    for (int j = 0; j < 4; ++j) {
      const int grow = grow0 + m * 16 + g * 4 + j;
      float v = 0.f;
      #pragma unroll
      for (int n = 0; n < 4; ++n) {
        const int gcol = gcol0 + n * 16 + r0;
        const float raw = acc[m][n][j];
        const float e = __expf(raw * TEMP_INV);
        if (grow != gcol) { v += e; cs[n] += e; }   // skip self-similarity
        if (pair && (grow + NPER == gcol)) {        // positive-pair raw dot
          s[grow] = raw;                            // dot(z_i, z_{i+NPER})
          s[gcol] = raw;                            // symmetric partner
        }
      }
      v += __shfl_xor(v, 1);
      v += __shfl_xor(v, 2);
      v += __shfl_xor(v, 4);
      v += __shfl_xor(v, 8);
      if (r0 == 0) racc[wc][wr * 64 + m * 16 + g * 4 + j] = v;
    }
  }
  #pragma unroll
  for (int n = 0; n < 4; ++n) {
    float v = cs[n];
    v += __shfl_xor(v, 16);
    v += __shfl_xor(v, 32);
    if (lane < 16) cacc[wr][wc * 64 + n * 16 + lane] = v;
  }
  __syncthreads();
  if (tid < 128) {
    atomicAdd(&rowsum[brow + tid], racc[0][tid] + racc[1][tid]);
  } else if (!diag) {
    const int i = tid - 128;
    atomicAdd(&rowsum[bcol + i], cacc[0][i] + cacc[1][i]);
  }
}

// ---------------------------------------------------------------------------
// Kernel 3: loss = mean_i( log(denom_i) - s_i/T ), 32 blocks + atomicAdd
// (out zeroed in k_normalize; stream order guarantees visibility).
// ---------------------------------------------------------------------------
__global__ __launch_bounds__(256) void k_loss(const float* __restrict__ rowsum,
                                              const float* __restrict__ s,
                                              float* __restrict__ out) {
  __shared__ float red[4];
  const int i = blockIdx.x * 256 + threadIdx.x;
  float v = logf(rowsum[i]) - s[i] * TEMP_INV;
  #pragma unroll
  for (int m = 1; m < 64; m <<= 1) v += __shfl_xor(v, m);
  const int w = threadIdx.x >> 6;
  if ((threadIdx.x & 63) == 0) red[w] = v;
  __syncthreads();
  if (threadIdx.x == 0)
    atomicAdd(out, (red[0] + red[1] + red[2] + red[3]) * (1.0f / (float)NROWS));
}

extern "C" void kernel_launch(void* const* d_in, const int* in_sizes, int n_in,
                              void* d_out, int out_size, void* d_ws, size_t ws_size,
                              hipStream_t stream) {
  const float* v0 = (const float*)d_in[0];
  const float* v1 = (const float*)d_in[1];
  float* out = (float*)d_out;

  unsigned short* z = (unsigned short*)d_ws;                    // 8192*512*2 B
  float* rowsum = (float*)((char*)d_ws + (size_t)NROWS * DIM * 2);
  float* s      = rowsum + NROWS;

  k_normalize<<<NROWS / 4, 256, 0, stream>>>(v0, v1, z, rowsum, out);
  k_gemm_sym<<<NBLK, 256, 0, stream>>>(z, rowsum, s);
  k_loss<<<NROWS / 256, 256, 0, stream>>>(rowsum, s, out);
}